// Round 1
// baseline (624.292 us; speedup 1.0000x reference)
//
#include <hip/hip_runtime.h>
#include <math.h>

#define Bb 8
#define Tt 2048
#define Cc 1024
#define Hh 64

// ---------------------------------------------------------------------------
// Kernel 1: fused QKV projection.  qkv[b,t,:] = x[b,t,:] @ {Wq,Wk,Wv}
// 32 rows per block, 256 threads: c = tid&63 (output col), rg = tid>>6,
// each thread computes rows rg, rg+4, ..., rg+28 for all 3 matrices.
// q is pre-scaled by H^-0.5 = 0.125 so attention skips the multiply.
// ---------------------------------------------------------------------------
__global__ __launch_bounds__(256)
void proj_kernel(const float* __restrict__ x,
                 const float* __restrict__ Wq,
                 const float* __restrict__ Wk,
                 const float* __restrict__ Wv,
                 float* __restrict__ qo,
                 float* __restrict__ ko,
                 float* __restrict__ vo)
{
    __shared__ float xs[32][36];          // +4 pad keeps float4 alignment, breaks bank stride
    const int tid  = threadIdx.x;
    const int row0 = blockIdx.x * 32;
    const int c    = tid & 63;
    const int rg   = tid >> 6;

    float accq[8], acck[8], accv[8];
    #pragma unroll
    for (int m = 0; m < 8; ++m) { accq[m] = 0.f; acck[m] = 0.f; accv[m] = 0.f; }

    for (int k0 = 0; k0 < Cc; k0 += 32) {
        // stage x tile: 32x32 floats, one float4 per thread, coalesced
        {
            const int rr = tid >> 3;
            const int kk = (tid & 7) << 2;
            *reinterpret_cast<float4*>(&xs[rr][kk]) =
                *reinterpret_cast<const float4*>(&x[(size_t)(row0 + rr) * Cc + k0 + kk]);
        }
        __syncthreads();

        #pragma unroll
        for (int ks = 0; ks < 32; ks += 4) {
            float wq[4], wk[4], wv[4];
            #pragma unroll
            for (int i = 0; i < 4; ++i) {
                const size_t wi = (size_t)(k0 + ks + i) * Hh + c;   // coalesced across lanes
                wq[i] = Wq[wi]; wk[i] = Wk[wi]; wv[i] = Wv[wi];
            }
            #pragma unroll
            for (int m = 0; m < 8; ++m) {
                // wave-uniform address -> LDS broadcast, no conflicts
                const float4 xv = *reinterpret_cast<const float4*>(&xs[rg + (m << 2)][ks]);
                accq[m] += xv.x * wq[0] + xv.y * wq[1] + xv.z * wq[2] + xv.w * wq[3];
                acck[m] += xv.x * wk[0] + xv.y * wk[1] + xv.z * wk[2] + xv.w * wk[3];
                accv[m] += xv.x * wv[0] + xv.y * wv[1] + xv.z * wv[2] + xv.w * wv[3];
            }
        }
        __syncthreads();
    }

    #pragma unroll
    for (int m = 0; m < 8; ++m) {
        const size_t r = (size_t)row0 + rg + (m << 2);
        qo[r * Hh + c] = accq[m] * 0.125f;     // fold softmax scale into q (exact: pow2)
        ko[r * Hh + c] = acck[m];
        vo[r * Hh + c] = accv[m];
    }
}

// ---------------------------------------------------------------------------
// Kernel 2: causal flash attention, fp32.
// Grid (T/64, B). Block = 256 threads handles a 64-row query tile, streams
// 64-key tiles up to the diagonal with online softmax.
// Thread layout: rg = tid>>4 (row group, 4 rows r0..r0+3),
//                jg = tid&15 (4 score cols / 4 output h-cols cg0..cg0+3).
// P is stored transposed in LDS so the PV phase reads P and V as float4.
// ---------------------------------------------------------------------------
__global__ __launch_bounds__(256)
void attn_kernel(const float* __restrict__ q,
                 const float* __restrict__ k,
                 const float* __restrict__ v,
                 float* __restrict__ out)
{
    __shared__ float qs[64][68];
    __shared__ float ks[64][68];
    __shared__ float vs[64][68];
    __shared__ float ps[64][68];          // ps[j][r] (transposed P)

    const int tid = threadIdx.x;
    const int b   = blockIdx.y;
    const int qt  = blockIdx.x;
    const int rg  = tid >> 4;
    const int jg  = tid & 15;
    const int r0  = rg << 2;
    const int cg0 = jg << 2;

    // load q tile (scale already folded in)
    {
        const int lr = tid >> 2;
        const int lc = (tid & 3) << 4;
        const float* src = &q[((size_t)b * Tt + (size_t)qt * 64 + lr) * Hh + lc];
        #pragma unroll
        for (int i = 0; i < 4; ++i)
            *reinterpret_cast<float4*>(&qs[lr][lc + (i << 2)]) =
                reinterpret_cast<const float4*>(src)[i];
    }

    float mrow[4], lrow[4], O[4][4];
    #pragma unroll
    for (int a = 0; a < 4; ++a) {
        mrow[a] = -INFINITY; lrow[a] = 0.f;
        #pragma unroll
        for (int c2 = 0; c2 < 4; ++c2) O[a][c2] = 0.f;
    }

    for (int kt = 0; kt <= qt; ++kt) {
        // stage k/v tiles
        {
            const int lr = tid >> 2;
            const int lc = (tid & 3) << 4;
            const size_t base = ((size_t)b * Tt + (size_t)kt * 64 + lr) * Hh + lc;
            #pragma unroll
            for (int i = 0; i < 4; ++i) {
                *reinterpret_cast<float4*>(&ks[lr][lc + (i << 2)]) =
                    *reinterpret_cast<const float4*>(&k[base + (i << 2)]);
                *reinterpret_cast<float4*>(&vs[lr][lc + (i << 2)]) =
                    *reinterpret_cast<const float4*>(&v[base + (i << 2)]);
            }
        }
        __syncthreads();   // also covers qs on first iteration

        // ---- scores: s[a][c2] = q[r0+a] . k[cg0+c2]
        float s[4][4];
        #pragma unroll
        for (int a = 0; a < 4; ++a)
            #pragma unroll
            for (int c2 = 0; c2 < 4; ++c2) s[a][c2] = 0.f;

        #pragma unroll 4
        for (int h = 0; h < Hh; h += 4) {
            float4 qv[4], kv[4];
            #pragma unroll
            for (int a = 0; a < 4; ++a)
                qv[a] = *reinterpret_cast<const float4*>(&qs[r0 + a][h]);
            #pragma unroll
            for (int c2 = 0; c2 < 4; ++c2)
                kv[c2] = *reinterpret_cast<const float4*>(&ks[cg0 + c2][h]);
            #pragma unroll
            for (int a = 0; a < 4; ++a)
                #pragma unroll
                for (int c2 = 0; c2 < 4; ++c2)
                    s[a][c2] += qv[a].x * kv[c2].x + qv[a].y * kv[c2].y +
                                qv[a].z * kv[c2].z + qv[a].w * kv[c2].w;
        }

        // causal mask (only the diagonal tile needs it: kt<qt is fully valid)
        if (kt == qt) {
            #pragma unroll
            for (int a = 0; a < 4; ++a)
                #pragma unroll
                for (int c2 = 0; c2 < 4; ++c2)
                    if (cg0 + c2 > r0 + a) s[a][c2] = -INFINITY;
        }

        // ---- online softmax update; row stats reduced over the 16 jg lanes
        float mnew[4], alpha[4], p[4][4];
        #pragma unroll
        for (int a = 0; a < 4; ++a) {
            float tm = fmaxf(fmaxf(s[a][0], s[a][1]), fmaxf(s[a][2], s[a][3]));
            #pragma unroll
            for (int off = 1; off < 16; off <<= 1)
                tm = fmaxf(tm, __shfl_xor(tm, off, 64));
            mnew[a]  = fmaxf(mrow[a], tm);
            alpha[a] = __expf(mrow[a] - mnew[a]);   // mrow=-inf -> 0, first tile safe
            float psum = 0.f;
            #pragma unroll
            for (int c2 = 0; c2 < 4; ++c2) {
                p[a][c2] = __expf(s[a][c2] - mnew[a]);   // masked -inf -> 0
                psum += p[a][c2];
            }
            #pragma unroll
            for (int off = 1; off < 16; off <<= 1)
                psum += __shfl_xor(psum, off, 64);
            lrow[a] = lrow[a] * alpha[a] + psum;
            mrow[a] = mnew[a];
        }

        // write P transposed: ps[j][r0..r0+3]
        #pragma unroll
        for (int c2 = 0; c2 < 4; ++c2) {
            const float4 pv = make_float4(p[0][c2], p[1][c2], p[2][c2], p[3][c2]);
            *reinterpret_cast<float4*>(&ps[cg0 + c2][r0]) = pv;
        }
        __syncthreads();

        // ---- PV: O[a][c2] += sum_j P[r0+a][j] * v[j][cg0+c2]
        #pragma unroll
        for (int a = 0; a < 4; ++a)
            #pragma unroll
            for (int c2 = 0; c2 < 4; ++c2) O[a][c2] *= alpha[a];

        #pragma unroll 8
        for (int j = 0; j < 64; ++j) {
            const float4 pv = *reinterpret_cast<const float4*>(&ps[j][r0]);
            const float4 vv = *reinterpret_cast<const float4*>(&vs[j][cg0]);
            const float pa[4] = {pv.x, pv.y, pv.z, pv.w};
            const float vb[4] = {vv.x, vv.y, vv.z, vv.w};
            #pragma unroll
            for (int a = 0; a < 4; ++a)
                #pragma unroll
                for (int c2 = 0; c2 < 4; ++c2)
                    O[a][c2] += pa[a] * vb[c2];
        }
        __syncthreads();   // protect ks/vs/ps before next tile's stage
    }

    // epilogue: normalize and store
    #pragma unroll
    for (int a = 0; a < 4; ++a) {
        const float inv = 1.f / lrow[a];
        const float4 ov = make_float4(O[a][0] * inv, O[a][1] * inv,
                                      O[a][2] * inv, O[a][3] * inv);
        *reinterpret_cast<float4*>(
            &out[((size_t)b * Tt + (size_t)qt * 64 + r0 + a) * Hh + cg0]) = ov;
    }
}

// ---------------------------------------------------------------------------
extern "C" void kernel_launch(void* const* d_in, const int* in_sizes, int n_in,
                              void* d_out, int out_size, void* d_ws, size_t ws_size,
                              hipStream_t stream)
{
    // setup_inputs order: x, Wk, Wq, Wv  (note Wk before Wq!)
    const float* x  = (const float*)d_in[0];
    const float* Wk = (const float*)d_in[1];
    const float* Wq = (const float*)d_in[2];
    const float* Wv = (const float*)d_in[3];
    float* out = (float*)d_out;

    const size_t n = (size_t)Bb * Tt * Hh;      // 1M elements per tensor
    float* qb = (float*)d_ws;                   // ws usage: 12 MB total
    float* kb = qb + n;
    float* vb = kb + n;

    proj_kernel<<<dim3((Bb * Tt) / 32), 256, 0, stream>>>(x, Wq, Wk, Wv, qb, kb, vb);
    attn_kernel<<<dim3(Tt / 64, Bb), 256, 0, stream>>>(qb, kb, vb, out);
}

// Round 2
// 154.468 us; speedup vs baseline: 4.0416x; 4.0416x over previous
//
#include <hip/hip_runtime.h>
#include <math.h>

#define Bb 8
#define Tt 2048
#define Cc 1024
#define Hh 64

typedef __attribute__((ext_vector_type(8))) short short8;
typedef __attribute__((ext_vector_type(4))) float f32x4;

// float -> bf16 bits, round-to-nearest-even
static __device__ __forceinline__ unsigned short f2bf(float f) {
    union { float f; unsigned u; } v; v.f = f;
    unsigned r = (v.u + 0x7FFFu + ((v.u >> 16) & 1u)) >> 16;
    return (unsigned short)r;
}

// ---------------------------------------------------------------------------
// Kernel 1: W -> bf16, transposed [192][1024].  n 0-63 = Wq*0.125, 64-127 = Wk,
// 128-191 = Wv.  Tiny (768 KB in), uncoalesced reads absorbed by L2.
// ---------------------------------------------------------------------------
__global__ __launch_bounds__(256)
void wconv_kernel(const float* __restrict__ Wk, const float* __restrict__ Wq,
                  const float* __restrict__ Wv, unsigned short* __restrict__ WbT)
{
    const int n = blockIdx.x;            // 0..191
    const int h = n & 63;
    const float* W; float scale = 1.0f;
    if (n < 64)       { W = Wq; scale = 0.125f; }   // fold softmax scale into q
    else if (n < 128) { W = Wk; }
    else              { W = Wv; }
    #pragma unroll
    for (int i = 0; i < 4; ++i) {
        const int k = threadIdx.x + (i << 8);
        WbT[n * 1024 + k] = f2bf(W[k * 64 + h] * scale);
    }
}

// ---------------------------------------------------------------------------
// Kernel 2: QKV projection via bf16 MFMA.  [16384,1024] x [1024,192].
// Tile 64(M) x 192(N) x 64(K-step).  512 threads = 8 waves (2M x 4N), each
// wave owns 2x3 16x16 fragments.  x converted fp32->bf16 during staging.
// LDS rows padded to 72 bf16 (144 B): frag ds_read_b128 is <=2-way (free).
// ---------------------------------------------------------------------------
__global__ __launch_bounds__(512)
void proj_kernel(const float* __restrict__ x, const unsigned short* __restrict__ WbT,
                 unsigned short* __restrict__ qb, unsigned short* __restrict__ kb,
                 unsigned short* __restrict__ vb)
{
    __shared__ unsigned short As[64][72];
    __shared__ unsigned short Bs[192][72];

    const int tid  = threadIdx.x;
    const int row0 = blockIdx.x * 64;
    const int lane = tid & 63;
    const int w    = tid >> 6;           // 0..7
    const int wm   = w >> 2;             // 0..1 -> M offset wm*32
    const int wn   = w & 3;              // 0..3 -> N offset wn*48
    const int fr   = lane & 15;          // frag row/col lane index
    const int fko  = (lane >> 4) << 3;   // frag k offset (8 elems)

    f32x4 acc[2][3];
    #pragma unroll
    for (int i = 0; i < 2; ++i)
        #pragma unroll
        for (int j = 0; j < 3; ++j) acc[i][j] = (f32x4){0.f, 0.f, 0.f, 0.f};

    for (int k0 = 0; k0 < Cc; k0 += 64) {
        // stage A: 64x64 fp32 -> bf16.  chunk = 16B of 4 floats, coalesced.
        #pragma unroll
        for (int i = 0; i < 2; ++i) {
            const int c  = tid + (i << 9);        // 0..1023
            const int r  = c >> 4;                // 0..63
            const int ko = (c & 15) << 2;         // 0..60 floats
            const float4 xv = *reinterpret_cast<const float4*>(
                &x[(size_t)(row0 + r) * Cc + k0 + ko]);
            ushort4 h4;
            h4.x = f2bf(xv.x); h4.y = f2bf(xv.y); h4.z = f2bf(xv.z); h4.w = f2bf(xv.w);
            *reinterpret_cast<ushort4*>(&As[r][ko]) = h4;
        }
        // stage B: 192x64 bf16, 16B chunks, coalesced (L2-resident after blk 0)
        #pragma unroll
        for (int i = 0; i < 3; ++i) {
            const int c  = tid + (i << 9);        // 0..1535
            const int r  = c >> 3;                // 0..191
            const int ko = (c & 7) << 3;          // 0..56 elems
            const short8 bv = *reinterpret_cast<const short8*>(
                &WbT[(size_t)r * 1024 + k0 + ko]);
            *reinterpret_cast<short8*>(&Bs[r][ko]) = bv;
        }
        __syncthreads();

        #pragma unroll
        for (int sub = 0; sub < 2; ++sub) {
            short8 af[2], bf[3];
            #pragma unroll
            for (int mf = 0; mf < 2; ++mf)
                af[mf] = *reinterpret_cast<const short8*>(
                    &As[wm * 32 + mf * 16 + fr][sub * 32 + fko]);
            #pragma unroll
            for (int nf = 0; nf < 3; ++nf)
                bf[nf] = *reinterpret_cast<const short8*>(
                    &Bs[wn * 48 + nf * 16 + fr][sub * 32 + fko]);
            #pragma unroll
            for (int mf = 0; mf < 2; ++mf)
                #pragma unroll
                for (int nf = 0; nf < 3; ++nf)
                    acc[mf][nf] = __builtin_amdgcn_mfma_f32_16x16x32_bf16(
                        af[mf], bf[nf], acc[mf][nf], 0, 0, 0);
        }
        __syncthreads();
    }

    // epilogue: C/D layout col=lane&15, row=(lane>>4)*4+reg
    #pragma unroll
    for (int mf = 0; mf < 2; ++mf)
        #pragma unroll
        for (int nf = 0; nf < 3; ++nf) {
            const int col = wn * 48 + nf * 16 + fr;   // 0..191, frag within one mat
            const int mat = col >> 6;
            const int h   = col & 63;
            unsigned short* dst = (mat == 0) ? qb : (mat == 1) ? kb : vb;
            #pragma unroll
            for (int r = 0; r < 4; ++r) {
                const int row = row0 + wm * 32 + mf * 16 + ((lane >> 4) << 2) + r;
                dst[(size_t)row * 64 + h] = f2bf(acc[mf][nf][r]);
            }
        }
}

// ---------------------------------------------------------------------------
// Kernel 3: transpose v [b][t][64] -> vt [b][64][2048] so PV B-frags are
// key-contiguous.  4 MB in + 4 MB out, LDS bounce, coalesced both sides.
// ---------------------------------------------------------------------------
__global__ __launch_bounds__(256)
void vtrans_kernel(const unsigned short* __restrict__ vb,
                   unsigned short* __restrict__ vt)
{
    __shared__ unsigned short ls[64][72];
    const int tid = threadIdx.x;
    const int t0  = blockIdx.x * 64;
    const int b   = blockIdx.y;

    #pragma unroll
    for (int i = 0; i < 2; ++i) {
        const int c  = tid + (i << 8);            // 0..511
        const int r  = c >> 3;                    // 0..63 token row
        const int ho = (c & 7) << 3;              // 0..56 h
        *reinterpret_cast<short8*>(&ls[r][ho]) =
            *reinterpret_cast<const short8*>(&vb[((size_t)b * Tt + t0 + r) * 64 + ho]);
    }
    __syncthreads();
    #pragma unroll
    for (int i = 0; i < 2; ++i) {
        const int c  = tid + (i << 8);
        const int h  = c >> 3;                    // 0..63
        const int to = (c & 7) << 3;              // 0..56 token
        short8 v;
        #pragma unroll
        for (int j = 0; j < 8; ++j) v[j] = (short)ls[to + j][h];
        *reinterpret_cast<short8*>(&vt[((size_t)b * 64 + h) * Tt + t0 + to]) = v;
    }
}

// ---------------------------------------------------------------------------
// Kernel 4: causal flash attention, bf16 MFMA.
// Grid (64,8), qt = 63-blockIdx.x (longest-first for tail packing).
// Block = 4 waves; Q-tile 32 rows; each wave owns key-tiles kt = w, w+4, ...
// (independent online softmax), combine (m,l,O) across waves in LDS at end.
// K/V frags read directly from global (L2-resident, 256 KB per batch).
// P re-layout C-frag -> A-frag via per-wave padded LDS slab.
// ---------------------------------------------------------------------------
__global__ __launch_bounds__(256)
void attn_kernel(const unsigned short* __restrict__ qb,
                 const unsigned short* __restrict__ kb,
                 const unsigned short* __restrict__ vt,
                 float* __restrict__ out)
{
    __shared__ float smem[9216];                  // 36 KB union: Ps | (Om,Ms,Ls)

    const int tid  = threadIdx.x;
    const int b    = blockIdx.y;
    const int qt   = 63 - blockIdx.x;             // longest blocks dispatch first
    const int lane = tid & 63;
    const int w    = tid >> 6;                    // 0..3
    const int fr   = lane & 15;
    const int fg   = lane >> 4;                   // 0..3
    const int fko  = fg << 3;
    const int ktmax = qt >> 1;

    // Q fragments, held in registers for the whole kernel
    short8 aq[2][2];
    #pragma unroll
    for (int mf = 0; mf < 2; ++mf)
        #pragma unroll
        for (int hs = 0; hs < 2; ++hs) {
            const size_t gq = (size_t)b * Tt + qt * 32 + mf * 16 + fr;
            aq[mf][hs] = *reinterpret_cast<const short8*>(&qb[gq * 64 + hs * 32 + fko]);
        }

    float mrun[2][4], lrun[2][4];
    f32x4 O[2][4];
    #pragma unroll
    for (int mf = 0; mf < 2; ++mf) {
        #pragma unroll
        for (int r = 0; r < 4; ++r) { mrun[mf][r] = -INFINITY; lrun[mf][r] = 0.f; }
        #pragma unroll
        for (int nh = 0; nh < 4; ++nh) O[mf][nh] = (f32x4){0.f, 0.f, 0.f, 0.f};
    }

    unsigned short* Pw = (unsigned short*)smem + w * 2304;   // [32][72] per wave

    for (int kt = w; kt <= ktmax; kt += 4) {
        // ---- load K fragments (8 x 16B) and V^T fragments (8 x 16B)
        short8 bk[4][2], bv[4][2];
        #pragma unroll
        for (int nf = 0; nf < 4; ++nf)
            #pragma unroll
            for (int hs = 0; hs < 2; ++hs) {
                const size_t gk = (size_t)b * Tt + kt * 64 + nf * 16 + fr;
                bk[nf][hs] = *reinterpret_cast<const short8*>(&kb[gk * 64 + hs * 32 + fko]);
            }
        #pragma unroll
        for (int nh = 0; nh < 4; ++nh)
            #pragma unroll
            for (int ks = 0; ks < 2; ++ks) {
                const size_t gv = ((size_t)b * 64 + nh * 16 + fr) * Tt
                                  + kt * 64 + ks * 32 + fko;
                bv[nh][ks] = *reinterpret_cast<const short8*>(&vt[gv]);
            }

        // ---- S = Q K^T  (scale pre-folded into q)
        const f32x4 zero = (f32x4){0.f, 0.f, 0.f, 0.f};
        f32x4 s[2][4];
        #pragma unroll
        for (int mf = 0; mf < 2; ++mf)
            #pragma unroll
            for (int nf = 0; nf < 4; ++nf) {
                f32x4 t = __builtin_amdgcn_mfma_f32_16x16x32_bf16(aq[mf][0], bk[nf][0], zero, 0, 0, 0);
                s[mf][nf] = __builtin_amdgcn_mfma_f32_16x16x32_bf16(aq[mf][1], bk[nf][1], t, 0, 0, 0);
            }

        // ---- causal mask: only the diagonal tile can be partial
        if (kt == ktmax) {
            #pragma unroll
            for (int mf = 0; mf < 2; ++mf)
                #pragma unroll
                for (int nf = 0; nf < 4; ++nf)
                    #pragma unroll
                    for (int r = 0; r < 4; ++r) {
                        const int key  = kt * 64 + nf * 16 + fr;
                        const int qrow = qt * 32 + mf * 16 + (fg << 2) + r;
                        if (key > qrow) s[mf][nf][r] = -INFINITY;
                    }
        }

        // ---- online softmax (row stats live in the 16-lane col groups)
        float alpha[2][4];
        #pragma unroll
        for (int mf = 0; mf < 2; ++mf)
            #pragma unroll
            for (int r = 0; r < 4; ++r) {
                float tmax = fmaxf(fmaxf(s[mf][0][r], s[mf][1][r]),
                                   fmaxf(s[mf][2][r], s[mf][3][r]));
                #pragma unroll
                for (int off = 1; off < 16; off <<= 1)
                    tmax = fmaxf(tmax, __shfl_xor(tmax, off, 64));
                const float mn = fmaxf(mrun[mf][r], tmax);   // finite: first tile always valid
                const float al = __expf(mrun[mf][r] - mn);   // -inf -> 0 on first tile
                float ps = 0.f;
                #pragma unroll
                for (int nf = 0; nf < 4; ++nf) {
                    const float pv = __expf(s[mf][nf][r] - mn);
                    s[mf][nf][r] = pv;
                    ps += pv;
                }
                #pragma unroll
                for (int off = 1; off < 16; off <<= 1)
                    ps += __shfl_xor(ps, off, 64);
                lrun[mf][r] = lrun[mf][r] * al + ps;
                mrun[mf][r] = mn;
                alpha[mf][r] = al;
            }

        // ---- P: C-layout regs -> per-wave LDS slab (A-frag layout)
        #pragma unroll
        for (int mf = 0; mf < 2; ++mf)
            #pragma unroll
            for (int nf = 0; nf < 4; ++nf)
                #pragma unroll
                for (int r = 0; r < 4; ++r)
                    Pw[(mf * 16 + (fg << 2) + r) * 72 + nf * 16 + fr] = f2bf(s[mf][nf][r]);

        // ---- rescale O, read P A-frags, PV MFMA
        #pragma unroll
        for (int mf = 0; mf < 2; ++mf) {
            const f32x4 av = (f32x4){alpha[mf][0], alpha[mf][1], alpha[mf][2], alpha[mf][3]};
            #pragma unroll
            for (int nh = 0; nh < 4; ++nh) O[mf][nh] *= av;
        }
        short8 pa[2][2];
        #pragma unroll
        for (int mf = 0; mf < 2; ++mf)
            #pragma unroll
            for (int ks = 0; ks < 2; ++ks)
                pa[mf][ks] = *reinterpret_cast<const short8*>(
                    &Pw[(mf * 16 + fr) * 72 + ks * 32 + fko]);
        #pragma unroll
        for (int mf = 0; mf < 2; ++mf)
            #pragma unroll
            for (int nh = 0; nh < 4; ++nh) {
                O[mf][nh] = __builtin_amdgcn_mfma_f32_16x16x32_bf16(pa[mf][0], bv[nh][0], O[mf][nh], 0, 0, 0);
                O[mf][nh] = __builtin_amdgcn_mfma_f32_16x16x32_bf16(pa[mf][1], bv[nh][1], O[mf][nh], 0, 0, 0);
            }
    }

    // ---- cross-wave combine.  Ps region is dead after this barrier.
    __syncthreads();
    float* Om = smem;                      // [4][32][68]
    float* Ms = smem + 8704;               // [4][32]
    float* Ls = smem + 8832;               // [4][32]
    #pragma unroll
    for (int mf = 0; mf < 2; ++mf)
        #pragma unroll
        for (int nh = 0; nh < 4; ++nh)
            #pragma unroll
            for (int r = 0; r < 4; ++r)
                Om[(w * 32 + mf * 16 + (fg << 2) + r) * 68 + nh * 16 + fr] = O[mf][nh][r];
    if (fr == 0) {
        #pragma unroll
        for (int mf = 0; mf < 2; ++mf)
            #pragma unroll
            for (int r = 0; r < 4; ++r) {
                Ms[w * 32 + mf * 16 + (fg << 2) + r] = mrun[mf][r];
                Ls[w * 32 + mf * 16 + (fg << 2) + r] = lrun[mf][r];
            }
    }
    __syncthreads();

    const int row = tid >> 3;              // 0..31
    const int h0  = (tid & 7) << 3;        // 0..56
    float M = -INFINITY;
    #pragma unroll
    for (int ww = 0; ww < 4; ++ww) M = fmaxf(M, Ms[ww * 32 + row]);
    float L = 0.f, o[8];
    #pragma unroll
    for (int j = 0; j < 8; ++j) o[j] = 0.f;
    #pragma unroll
    for (int ww = 0; ww < 4; ++ww) {
        const float sc = __expf(Ms[ww * 32 + row] - M);   // idle wave: -inf -> 0
        L += Ls[ww * 32 + row] * sc;
        const float4 a = *reinterpret_cast<const float4*>(&Om[(ww * 32 + row) * 68 + h0]);
        const float4 c = *reinterpret_cast<const float4*>(&Om[(ww * 32 + row) * 68 + h0 + 4]);
        o[0] += a.x * sc; o[1] += a.y * sc; o[2] += a.z * sc; o[3] += a.w * sc;
        o[4] += c.x * sc; o[5] += c.y * sc; o[6] += c.z * sc; o[7] += c.w * sc;
    }
    const float invL = 1.f / L;
    float* dst = &out[((size_t)b * Tt + qt * 32 + row) * 64 + h0];
    *reinterpret_cast<float4*>(dst)     = make_float4(o[0]*invL, o[1]*invL, o[2]*invL, o[3]*invL);
    *reinterpret_cast<float4*>(dst + 4) = make_float4(o[4]*invL, o[5]*invL, o[6]*invL, o[7]*invL);
}

// ---------------------------------------------------------------------------
extern "C" void kernel_launch(void* const* d_in, const int* in_sizes, int n_in,
                              void* d_out, int out_size, void* d_ws, size_t ws_size,
                              hipStream_t stream)
{
    // setup_inputs order: x, Wk, Wq, Wv
    const float* x  = (const float*)d_in[0];
    const float* Wk = (const float*)d_in[1];
    const float* Wq = (const float*)d_in[2];
    const float* Wv = (const float*)d_in[3];
    float* out = (float*)d_out;

    const size_t n = (size_t)Bb * Tt * Hh;              // 1M elems per tensor
    unsigned short* WbT = (unsigned short*)d_ws;        // 192*1024 = 196608
    unsigned short* qb  = WbT + 196608;
    unsigned short* kb  = qb + n;
    unsigned short* vb  = kb + n;
    unsigned short* vt  = vb + n;                       // transposed V

    wconv_kernel <<<dim3(192),      256, 0, stream>>>(Wk, Wq, Wv, WbT);
    proj_kernel  <<<dim3(256),      512, 0, stream>>>(x, WbT, qb, kb, vb);
    vtrans_kernel<<<dim3(32, 8),    256, 0, stream>>>(vb, vt);
    attn_kernel  <<<dim3(64, 8),    256, 0, stream>>>(qb, kb, vt, out);
}

// Round 4
// 140.529 us; speedup vs baseline: 4.4424x; 1.0992x over previous
//
#include <hip/hip_runtime.h>
#include <math.h>

#define Bb 8
#define Tt 2048
#define Cc 1024
#define Hh 64

typedef __attribute__((ext_vector_type(8))) short short8;
typedef __attribute__((ext_vector_type(4))) float f32x4;

// float -> bf16 bits, round-to-nearest-even
static __device__ __forceinline__ unsigned short f2bf(float f) {
    union { float f; unsigned u; } v; v.f = f;
    return (unsigned short)((v.u + 0x7FFFu + ((v.u >> 16) & 1u)) >> 16);
}

#define LOG2E 1.44269504088896340736f

// ---------------------------------------------------------------------------
// Kernel 1: W -> bf16, transposed [192][1024].  n 0-63 = Wq*(0.125*log2e)
// (softmax scale AND exp2-domain conversion folded into q), 64-127 = Wk,
// 128-191 = Wv.
// ---------------------------------------------------------------------------
__global__ __launch_bounds__(256)
void wconv_kernel(const float* __restrict__ Wk, const float* __restrict__ Wq,
                  const float* __restrict__ Wv, unsigned short* __restrict__ WbT)
{
    const int n = blockIdx.x;            // 0..191
    const int h = n & 63;
    const float* W; float scale = 1.0f;
    if (n < 64)       { W = Wq; scale = 0.125f * LOG2E; }
    else if (n < 128) { W = Wk; }
    else              { W = Wv; }
    #pragma unroll
    for (int i = 0; i < 4; ++i) {
        const int k = threadIdx.x + (i << 8);
        WbT[n * 1024 + k] = f2bf(W[k * 64 + h] * scale);
    }
}

// ---------------------------------------------------------------------------
// Kernel 2: QKV projection, bf16 MFMA.  [16384,1024] x [1024,192].
// Tile 32(M) x 192(N), K-step 64.  256 threads = 4 waves, wave w owns cols
// w*48..w*48+47 (2 m-frags x 3 n-frags).  Grid 512 -> 2 blocks/CU so one
// block's MFMA covers the other's stage drain (round-2 was 1/CU, stall-bound).
// v is written TRANSPOSED to vt[b][h][t] straight from the epilogue
// (C-layout gives 4 consecutive t per lane -> ushort4), deleting vtrans.
// ---------------------------------------------------------------------------
__global__ __launch_bounds__(256)
void proj_kernel(const float* __restrict__ x, const unsigned short* __restrict__ WbT,
                 unsigned short* __restrict__ qb, unsigned short* __restrict__ kb,
                 unsigned short* __restrict__ vt)
{
    __shared__ unsigned short As[32][72];
    __shared__ unsigned short Bs[192][72];

    const int tid  = threadIdx.x;
    const int row0 = blockIdx.x * 32;
    const int lane = tid & 63;
    const int w    = tid >> 6;           // 0..3 -> N offset w*48
    const int fr   = lane & 15;
    const int fg   = lane >> 4;          // 0..3
    const int fko  = fg << 3;

    f32x4 acc[2][3];
    #pragma unroll
    for (int i = 0; i < 2; ++i)
        #pragma unroll
        for (int j = 0; j < 3; ++j) acc[i][j] = (f32x4){0.f, 0.f, 0.f, 0.f};

    for (int k0 = 0; k0 < Cc; k0 += 64) {
        // stage A: 32x64 fp32 -> bf16.  8 fp32 per thread -> one b128 write.
        {
            const int r  = tid >> 3;              // 0..31
            const int ko = (tid & 7) << 3;        // 0..56
            const float* src = &x[(size_t)(row0 + r) * Cc + k0 + ko];
            const float4 a0 = *reinterpret_cast<const float4*>(src);
            const float4 a1 = *reinterpret_cast<const float4*>(src + 4);
            short8 h8;
            h8[0] = (short)f2bf(a0.x); h8[1] = (short)f2bf(a0.y);
            h8[2] = (short)f2bf(a0.z); h8[3] = (short)f2bf(a0.w);
            h8[4] = (short)f2bf(a1.x); h8[5] = (short)f2bf(a1.y);
            h8[6] = (short)f2bf(a1.z); h8[7] = (short)f2bf(a1.w);
            *reinterpret_cast<short8*>(&As[r][ko]) = h8;
        }
        // stage B: 192x64 bf16 (L2-resident WbT), 6 b128 chunks per thread
        #pragma unroll
        for (int i = 0; i < 6; ++i) {
            const int c  = tid + (i << 8);        // 0..1535
            const int r  = c >> 3;                // 0..191
            const int ko = (c & 7) << 3;          // 0..56
            *reinterpret_cast<short8*>(&Bs[r][ko]) =
                *reinterpret_cast<const short8*>(&WbT[(size_t)r * 1024 + k0 + ko]);
        }
        __syncthreads();

        #pragma unroll
        for (int sub = 0; sub < 2; ++sub) {
            short8 af[2], bf[3];
            #pragma unroll
            for (int mf = 0; mf < 2; ++mf)
                af[mf] = *reinterpret_cast<const short8*>(
                    &As[mf * 16 + fr][sub * 32 + fko]);
            #pragma unroll
            for (int nf = 0; nf < 3; ++nf)
                bf[nf] = *reinterpret_cast<const short8*>(
                    &Bs[w * 48 + nf * 16 + fr][sub * 32 + fko]);
            #pragma unroll
            for (int mf = 0; mf < 2; ++mf)
                #pragma unroll
                for (int nf = 0; nf < 3; ++nf)
                    acc[mf][nf] = __builtin_amdgcn_mfma_f32_16x16x32_bf16(
                        af[mf], bf[nf], acc[mf][nf], 0, 0, 0);
        }
        __syncthreads();
    }

    // epilogue: C/D layout col=lane&15, row=fg*4+reg
    #pragma unroll
    for (int mf = 0; mf < 2; ++mf)
        #pragma unroll
        for (int nf = 0; nf < 3; ++nf) {
            const int col  = w * 48 + nf * 16 + fr;   // 0..191
            const int mat  = col >> 6;
            const int h    = col & 63;
            const int rowb = row0 + mf * 16 + (fg << 2);
            if (mat == 2) {
                // v -> vt[b][h][t], 4 consecutive t = one ushort4
                const int bb = rowb >> 11;
                const int t  = rowb & 2047;
                ushort4 pk;
                pk.x = f2bf(acc[mf][nf][0]); pk.y = f2bf(acc[mf][nf][1]);
                pk.z = f2bf(acc[mf][nf][2]); pk.w = f2bf(acc[mf][nf][3]);
                *reinterpret_cast<ushort4*>(&vt[((size_t)bb * 64 + h) * Tt + t]) = pk;
            } else {
                unsigned short* dst = mat ? kb : qb;
                #pragma unroll
                for (int r = 0; r < 4; ++r)
                    dst[(size_t)(rowb + r) * 64 + h] = f2bf(acc[mf][nf][r]);
            }
        }
}

// ---------------------------------------------------------------------------
// Kernel 3: causal flash attention, bf16 MFMA, SWAPPED QK^T.
// Grid 512: b = fid&7 (one batch per XCD -> K/V/Q L2-resident),
// qt = 63-(fid>>3) (longest-first).  4 waves split key tiles (kt = w, w+4,..).
// S^T = mfma(K,Q): lane owns q-row (col fr), keys in regs -> serial fmax +
// 2 shfl row-reduce, alpha lane-local, P store is 8 packed ds_write_b64.
// PV reads P back as b128 A-frags (unchanged).  exp2 domain throughout.
// ---------------------------------------------------------------------------
__global__ __launch_bounds__(256)
void attn_kernel(const unsigned short* __restrict__ qb,
                 const unsigned short* __restrict__ kb,
                 const unsigned short* __restrict__ vt,
                 float* __restrict__ out)
{
    __shared__ float smem[9216];                  // 36 KB union: Pw | (Om,Ms,Ls)

    const int tid  = threadIdx.x;
    const int fid  = blockIdx.x;
    const int b    = fid & 7;                     // XCD-matched batch
    const int qt   = 63 - (fid >> 3);             // longest-first
    const int lane = tid & 63;
    const int w    = tid >> 6;                    // 0..3
    const int fr   = lane & 15;
    const int fg   = lane >> 4;                   // 0..3
    const int fko  = fg << 3;
    const int ktmax = qt >> 1;

    // Q B-frags (B[k=h][n=qrow]: lane holds qrow n*16+fr, h contiguous)
    short8 aq[2][2];
    #pragma unroll
    for (int n = 0; n < 2; ++n)
        #pragma unroll
        for (int hs = 0; hs < 2; ++hs) {
            const size_t gq = (size_t)b * Tt + qt * 32 + n * 16 + fr;
            aq[n][hs] = *reinterpret_cast<const short8*>(&qb[gq * 64 + hs * 32 + fko]);
        }

    float mrun[2] = {-INFINITY, -INFINITY}, lrun[2] = {0.f, 0.f};
    f32x4 O[2][4];
    #pragma unroll
    for (int mf = 0; mf < 2; ++mf)
        #pragma unroll
        for (int nh = 0; nh < 4; ++nh) O[mf][nh] = (f32x4){0.f, 0.f, 0.f, 0.f};

    unsigned short* Pw = (unsigned short*)smem + w * 2304;   // [32][72] per wave

    for (int kt = w; kt <= ktmax; kt += 4) {
        // K A-frags (A[key][h]) and V^T B-frags (B^T[h][key], key contig)
        short8 bk[4][2], bv[4][2];
        #pragma unroll
        for (int kf = 0; kf < 4; ++kf)
            #pragma unroll
            for (int hs = 0; hs < 2; ++hs) {
                const size_t gk = (size_t)b * Tt + kt * 64 + kf * 16 + fr;
                bk[kf][hs] = *reinterpret_cast<const short8*>(&kb[gk * 64 + hs * 32 + fko]);
            }
        #pragma unroll
        for (int nh = 0; nh < 4; ++nh)
            #pragma unroll
            for (int ks = 0; ks < 2; ++ks) {
                const size_t gv = ((size_t)b * 64 + nh * 16 + fr) * Tt
                                  + kt * 64 + ks * 32 + fko;
                bv[nh][ks] = *reinterpret_cast<const short8*>(&vt[gv]);
            }

        // ---- S^T = K Q^T : st[kf][n], row=key=kf*16+fg*4+r, col=qrow=n*16+fr
        const f32x4 zero = (f32x4){0.f, 0.f, 0.f, 0.f};
        f32x4 st[4][2];
        #pragma unroll
        for (int kf = 0; kf < 4; ++kf)
            #pragma unroll
            for (int n = 0; n < 2; ++n) {
                f32x4 t = __builtin_amdgcn_mfma_f32_16x16x32_bf16(bk[kf][0], aq[n][0], zero, 0, 0, 0);
                st[kf][n] = __builtin_amdgcn_mfma_f32_16x16x32_bf16(bk[kf][1], aq[n][1], t, 0, 0, 0);
            }

        // causal mask (diagonal tile only)
        if (kt == ktmax) {
            #pragma unroll
            for (int kf = 0; kf < 4; ++kf)
                #pragma unroll
                for (int n = 0; n < 2; ++n)
                    #pragma unroll
                    for (int r = 0; r < 4; ++r) {
                        const int key  = kt * 64 + kf * 16 + (fg << 2) + r;
                        const int qrow = qt * 32 + n * 16 + fr;
                        if (key > qrow) st[kf][n][r] = -INFINITY;
                    }
        }

        // ---- online softmax: lane owns q-row, reduce 16 regs + 2 shfl
        float alpha[2];
        #pragma unroll
        for (int n = 0; n < 2; ++n) {
            float tmax = -INFINITY;
            #pragma unroll
            for (int kf = 0; kf < 4; ++kf)
                #pragma unroll
                for (int r = 0; r < 4; ++r) tmax = fmaxf(tmax, st[kf][n][r]);
            tmax = fmaxf(tmax, __shfl_xor(tmax, 16, 64));
            tmax = fmaxf(tmax, __shfl_xor(tmax, 32, 64));
            const float mn = fmaxf(mrun[n], tmax);     // finite after full reduce
            const float al = exp2f(mrun[n] - mn);      // -inf -> 0 first tile
            float psum = 0.f;
            #pragma unroll
            for (int kf = 0; kf < 4; ++kf)
                #pragma unroll
                for (int r = 0; r < 4; ++r) {
                    const float pv = exp2f(st[kf][n][r] - mn);
                    st[kf][n][r] = pv;
                    psum += pv;
                }
            psum += __shfl_xor(psum, 16, 64);
            psum += __shfl_xor(psum, 32, 64);
            lrun[n] = lrun[n] * al + psum;
            mrun[n] = mn;
            alpha[n] = al;
        }

        // ---- P store: lane's 4 consecutive keys per frag -> ds_write_b64 x8
        #pragma unroll
        for (int kf = 0; kf < 4; ++kf)
            #pragma unroll
            for (int n = 0; n < 2; ++n) {
                ushort4 pk;
                pk.x = f2bf(st[kf][n][0]); pk.y = f2bf(st[kf][n][1]);
                pk.z = f2bf(st[kf][n][2]); pk.w = f2bf(st[kf][n][3]);
                *reinterpret_cast<ushort4*>(
                    &Pw[(n * 16 + fr) * 72 + kf * 16 + (fg << 2)]) = pk;
            }

        // ---- alpha: col-layout -> row-layout via shfl, rescale O
        #pragma unroll
        for (int mf = 0; mf < 2; ++mf) {
            f32x4 av;
            #pragma unroll
            for (int r = 0; r < 4; ++r)
                av[r] = __shfl(alpha[mf], (fg << 2) + r, 64);
            #pragma unroll
            for (int nh = 0; nh < 4; ++nh) O[mf][nh] *= av;
        }

        // ---- PV: read P as A-frags (b128), MFMA with V^T B-frags
        short8 pa[2][2];
        #pragma unroll
        for (int mf = 0; mf < 2; ++mf)
            #pragma unroll
            for (int ks = 0; ks < 2; ++ks)
                pa[mf][ks] = *reinterpret_cast<const short8*>(
                    &Pw[(mf * 16 + fr) * 72 + ks * 32 + fko]);
        #pragma unroll
        for (int mf = 0; mf < 2; ++mf)
            #pragma unroll
            for (int nh = 0; nh < 4; ++nh) {
                O[mf][nh] = __builtin_amdgcn_mfma_f32_16x16x32_bf16(pa[mf][0], bv[nh][0], O[mf][nh], 0, 0, 0);
                O[mf][nh] = __builtin_amdgcn_mfma_f32_16x16x32_bf16(pa[mf][1], bv[nh][1], O[mf][nh], 0, 0, 0);
            }
    }

    // ---- cross-wave combine
    __syncthreads();
    float* Om = smem;                      // [4][32][68]
    float* Ms = smem + 8704;               // [4][32]
    float* Ls = smem + 8832;               // [4][32]
    #pragma unroll
    for (int mf = 0; mf < 2; ++mf)
        #pragma unroll
        for (int nh = 0; nh < 4; ++nh)
            #pragma unroll
            for (int r = 0; r < 4; ++r)
                Om[(w * 32 + mf * 16 + (fg << 2) + r) * 68 + nh * 16 + fr] = O[mf][nh][r];
    if (fg == 0) {
        #pragma unroll
        for (int n = 0; n < 2; ++n) {
            Ms[w * 32 + n * 16 + fr] = mrun[n];
            Ls[w * 32 + n * 16 + fr] = lrun[n];
        }
    }
    __syncthreads();

    const int row = tid >> 3;              // 0..31
    const int h0  = (tid & 7) << 3;        // 0..56
    float M = -INFINITY;
    #pragma unroll
    for (int ww = 0; ww < 4; ++ww) M = fmaxf(M, Ms[ww * 32 + row]);
    float L = 0.f, o[8];
    #pragma unroll
    for (int j = 0; j < 8; ++j) o[j] = 0.f;
    #pragma unroll
    for (int ww = 0; ww < 4; ++ww) {
        const float sc = exp2f(Ms[ww * 32 + row] - M);   // idle wave: -inf -> 0
        L += Ls[ww * 32 + row] * sc;
        const float4 a = *reinterpret_cast<const float4*>(&Om[(ww * 32 + row) * 68 + h0]);
        const float4 c = *reinterpret_cast<const float4*>(&Om[(ww * 32 + row) * 68 + h0 + 4]);
        o[0] += a.x * sc; o[1] += a.y * sc; o[2] += a.z * sc; o[3] += a.w * sc;
        o[4] += c.x * sc; o[5] += c.y * sc; o[6] += c.z * sc; o[7] += c.w * sc;
    }
    const float invL = 1.f / L;
    float* dst = &out[((size_t)b * Tt + qt * 32 + row) * 64 + h0];
    *reinterpret_cast<float4*>(dst)     = make_float4(o[0]*invL, o[1]*invL, o[2]*invL, o[3]*invL);
    *reinterpret_cast<float4*>(dst + 4) = make_float4(o[4]*invL, o[5]*invL, o[6]*invL, o[7]*invL);
}

// ---------------------------------------------------------------------------
extern "C" void kernel_launch(void* const* d_in, const int* in_sizes, int n_in,
                              void* d_out, int out_size, void* d_ws, size_t ws_size,
                              hipStream_t stream)
{
    // setup_inputs order: x, Wk, Wq, Wv
    const float* x  = (const float*)d_in[0];
    const float* Wk = (const float*)d_in[1];
    const float* Wq = (const float*)d_in[2];
    const float* Wv = (const float*)d_in[3];
    float* out = (float*)d_out;

    const size_t n = (size_t)Bb * Tt * Hh;              // 1M elems per tensor
    unsigned short* WbT = (unsigned short*)d_ws;        // 192*1024
    unsigned short* qb  = WbT + 196608;
    unsigned short* kb  = qb + n;
    unsigned short* vt  = kb + n;                       // V^T [b][h][t]

    wconv_kernel<<<dim3(192), 256, 0, stream>>>(Wk, Wq, Wv, WbT);
    proj_kernel <<<dim3(512), 256, 0, stream>>>(x, WbT, qb, kb, vt);
    attn_kernel <<<dim3(512), 256, 0, stream>>>(qb, kb, vt, out);
}